// Round 3
// baseline (653.923 us; speedup 1.0000x reference)
//
#include <hip/hip_runtime.h>

// Helmholtz multigrid (MREFIN=6, NU1=NU2=2, NCYC=2) on 64x1x513x513 f32.
// Round 2: dead-code-eliminated schedule (reference's scrambled upsweep makes
// levels >=2 and all upsweep relaxes of levels 1..5 dead). Live work per cycle:
//   psi0 = relax^2(psi0,q0); q1 = rescal(psi0,q0); psi1 = relax^2(0,q1);
//   psi0 = relax^2(psi0 + prolong(psi1), q0)
// All FP orders match the reference elementwise ops.

#define BTX 64
#define BTY 32

__global__ void init_kernel(const float4* __restrict__ psig, const float4* __restrict__ qin,
                            float4* __restrict__ psi0, float4* __restrict__ q0,
                            int n4, float h0sq) {
    int t = blockIdx.x * blockDim.x + threadIdx.x;
    if (t >= n4) return;
    psi0[t] = psig[t];
    float4 v = qin[t];
    v.x *= h0sq; v.y *= h0sq; v.z *= h0sq; v.w *= h0sq;
    q0[t] = v;
}

// Fused: pout = relax(relax(pin,q),q) ; qc = rescal(pout, q)  (level 0 downsweep)
__global__ __launch_bounds__(256) void relax2_rescal_kernel(
    const float* __restrict__ pin, const float* __restrict__ q,
    float* __restrict__ pout, float* __restrict__ qc,
    int n, int nc, float inv, float c)
{
    __shared__ float sq[BTY + 4][BTX + 4];
    __shared__ float s1[BTY + 4][BTX + 4];
    __shared__ float s2[BTY + 2][BTX + 2];
    const int bx0 = blockIdx.x * BTX;
    const int by0 = blockIdx.y * BTY;
    const size_t base = (size_t)blockIdx.z * n * n;
    const size_t cbase = (size_t)blockIdx.z * nc * nc;
    const int tid = threadIdx.y * 64 + threadIdx.x;

    // stage 1 (+ q cache) over halo-2 region [by0-2, by0+BTY+1] x [bx0-2, bx0+BTX+1]
    for (int idx = tid; idx < (BTY + 4) * (BTX + 4); idx += 256) {
        int ly = idx / (BTX + 4), lx = idx - ly * (BTX + 4);
        int gy = by0 - 2 + ly, gx = bx0 - 2 + lx;
        float qv = 0.0f, v = 0.0f;
        if (gy >= 0 && gy < n && gx >= 0 && gx < n) {
            size_t p = base + (size_t)gy * n + gx;
            qv = q[p];
            if (gy >= 1 && gy < n - 1 && gx >= 1 && gx < n - 1)
                v = inv * ((((pin[p - n] + pin[p + n]) + pin[p - 1]) + pin[p + 1]) - qv);
        }
        sq[ly][lx] = qv;
        s1[ly][lx] = v;
    }
    __syncthreads();
    // stage 2 over halo-1 region [by0-1, by0+BTY] x [bx0-1, bx0+BTX]
    for (int idx = tid; idx < (BTY + 2) * (BTX + 2); idx += 256) {
        int ly = idx / (BTX + 2), lx = idx - ly * (BTX + 2);
        int gy = by0 - 1 + ly, gx = bx0 - 1 + lx;
        float v = 0.0f;
        if (gy >= 1 && gy < n - 1 && gx >= 1 && gx < n - 1)
            v = inv * ((((s1[ly][lx + 1] + s1[ly + 2][lx + 1]) + s1[ly + 1][lx]) + s1[ly + 1][lx + 2])
                       - sq[ly + 1][lx + 1]);
        s2[ly][lx] = v;
    }
    __syncthreads();
    // write relaxed psi (full coverage incl. ring=0)
    for (int idx = tid; idx < BTY * BTX; idx += 256) {
        int ly = idx / BTX, lx = idx - ly * BTX;
        int gy = by0 + ly, gx = bx0 + lx;
        if (gy < n && gx < n)
            pout[base + (size_t)gy * n + gx] = s2[ly + 1][lx + 1];
    }
    // rescal from LDS stage-2 values: coarse (ic,jc) with fine center (2ic,2jc) in tile
    for (int idx = tid; idx < (BTY / 2) * (BTX / 2); idx += 256) {
        int lyc = idx / (BTX / 2), lxc = idx - lyc * (BTX / 2);
        int fy = by0 + 2 * lyc, fx = bx0 + 2 * lxc;
        if (fy >= n || fx >= n) continue;
        int ic = fy >> 1, jc = fx >> 1;
        float outv = 0.0f;
        if (ic > 0 && ic < nc - 1 && jc > 0 && jc < nc - 1) {
            float ctr = s2[2 * lyc + 1][2 * lxc + 1];
            float up  = s2[2 * lyc    ][2 * lxc + 1];
            float dn  = s2[2 * lyc + 2][2 * lxc + 1];
            float lf  = s2[2 * lyc + 1][2 * lxc    ];
            float rt  = s2[2 * lyc + 1][2 * lxc + 2];
            float qv  = sq[2 * lyc + 2][2 * lxc + 2];
            outv = 4.0f * (((((c * ctr - up) - dn) - lf) - rt) + qv);
        }
        qc[cbase + (size_t)ic * nc + jc] = outv;
    }
}

// psi1 = relax(relax(0,q),q): stage-1 = inv*(0-q) recomputed per neighbor (bitwise same)
__global__ void relax2_zero_kernel(const float* __restrict__ q, float* __restrict__ pout,
                                   int n, float inv) {
    int j = blockIdx.x * blockDim.x + threadIdx.x;
    int i = blockIdx.y;
    int b = blockIdx.z;
    if (j >= n) return;
    size_t p = ((size_t)b * n + i) * n + j;
    float v = 0.0f;
    if (i >= 1 && i < n - 1 && j >= 1 && j < n - 1) {
        float su = (i >= 2)     ? inv * (0.0f - q[p - n]) : 0.0f;
        float sd = (i <= n - 3) ? inv * (0.0f - q[p + n]) : 0.0f;
        float sl = (j >= 2)     ? inv * (0.0f - q[p - 1]) : 0.0f;
        float sr = (j <= n - 3) ? inv * (0.0f - q[p + 1]) : 0.0f;
        v = inv * ((((su + sd) + sl) + sr) - q[p]);
    }
    pout[p] = v;
}

// pout = relax^2(pin + prolong(coarse), q)   (level 0 upsweep tail)
__global__ __launch_bounds__(256) void relax2_prolong_kernel(
    const float* __restrict__ pin, const float* __restrict__ q,
    const float* __restrict__ coarse,
    float* __restrict__ pout, int n, int nc, float inv)
{
    __shared__ float spe[BTY + 4][BTX + 4];
    __shared__ float sq[BTY + 2][BTX + 2];
    __shared__ float s1[BTY + 2][BTX + 2];
    const int bx0 = blockIdx.x * BTX;
    const int by0 = blockIdx.y * BTY;
    const size_t base = (size_t)blockIdx.z * n * n;
    const size_t cbase = (size_t)blockIdx.z * nc * nc;
    const int tid = threadIdx.y * 64 + threadIdx.x;

    // pe = pin + bilinear(coarse) over halo-2 region
    for (int idx = tid; idx < (BTY + 4) * (BTX + 4); idx += 256) {
        int ly = idx / (BTX + 4), lx = idx - ly * (BTX + 4);
        int gy = by0 - 2 + ly, gx = bx0 - 2 + lx;
        float v = 0.0f;
        if (gy >= 0 && gy < n && gx >= 0 && gx < n) {
            size_t p = base + (size_t)gy * n + gx;
            int ci = gy >> 1, cj = gx >> 1;
            int io = gy & 1, jo = gx & 1;
            size_t c0 = cbase + (size_t)ci * nc + cj;
            float pv;
            if (!io && !jo)      pv = coarse[c0];
            else if (io && !jo)  pv = 0.5f * (coarse[c0] + coarse[c0 + nc]);
            else if (!io && jo)  pv = 0.5f * (coarse[c0] + coarse[c0 + 1]);
            else                 pv = 0.25f * (((coarse[c0] + coarse[c0 + 1]) + coarse[c0 + nc]) + coarse[c0 + nc + 1]);
            v = pin[p] + pv;
        }
        spe[ly][lx] = v;
    }
    __syncthreads();
    // stage 1 over halo-1 region
    for (int idx = tid; idx < (BTY + 2) * (BTX + 2); idx += 256) {
        int ly = idx / (BTX + 2), lx = idx - ly * (BTX + 2);
        int gy = by0 - 1 + ly, gx = bx0 - 1 + lx;
        float qv = 0.0f, v = 0.0f;
        if (gy >= 0 && gy < n && gx >= 0 && gx < n) {
            size_t p = base + (size_t)gy * n + gx;
            qv = q[p];
            if (gy >= 1 && gy < n - 1 && gx >= 1 && gx < n - 1)
                v = inv * ((((spe[ly][lx + 1] + spe[ly + 2][lx + 1]) + spe[ly + 1][lx]) + spe[ly + 1][lx + 2]) - qv);
        }
        sq[ly][lx] = qv;
        s1[ly][lx] = v;
    }
    __syncthreads();
    // stage 2 -> global (full coverage incl. ring=0)
    for (int idx = tid; idx < BTY * BTX; idx += 256) {
        int ly = idx / BTX, lx = idx - ly * BTX;
        int gy = by0 + ly, gx = bx0 + lx;
        if (gy >= n || gx >= n) continue;
        float v = 0.0f;
        if (gy >= 1 && gy < n - 1 && gx >= 1 && gx < n - 1)
            v = inv * ((((s1[ly][lx + 1] + s1[ly + 2][lx + 1]) + s1[ly + 1][lx]) + s1[ly + 1][lx + 2])
                       - sq[ly + 1][lx + 1]);
        pout[base + (size_t)gy * n + gx] = v;
    }
}

extern "C" void kernel_launch(void* const* d_in, const int* in_sizes, int n_in,
                              void* d_out, int out_size, void* d_ws, size_t ws_size,
                              hipStream_t stream) {
    const float* PSIG = (const float*)d_in[0];
    const float* QIN  = (const float*)d_in[1];
    float* out = (float*)d_out;
    float* ws  = (float*)d_ws;

    const int B = 64;
    const int n0 = 513, n1 = 257;
    // h in double, constants cast to f32 exactly like np.float32
    const double h0 = 0.015625, h1 = 0.03125;
    const float inv0 = (float)(1.0 / (4.0 + h0 * h0));
    const float c0   = (float)(4.0 + h0 * h0);
    const float inv1 = (float)(1.0 / (4.0 + h1 * h1));
    const size_t E0 = (size_t)B * n0 * n0;   // 16,842,816
    const size_t E1 = (size_t)B * n1 * n1;   //  4,227,136

    size_t off = 0;
    auto alloc = [&](size_t e) -> float* {
        float* p = ws + off;
        off += (e + 63) & ~(size_t)63;
        return p;
    };
    float* q0   = alloc(E0);
    float* q1   = alloc(E1);
    float* psiB = alloc(E0);
    float* psi1 = alloc(E1);

    float* curA = out;   // psi0 ping-pong: A -> B -> A per cycle (2 swaps), final in A=d_out
    float* curB = psiB;

    {
        int n4 = (int)(E0 / 4);
        dim3 g((n4 + 255) / 256), blk(256);
        init_kernel<<<g, blk, 0, stream>>>((const float4*)PSIG, (const float4*)QIN,
                                           (float4*)curA, (float4*)q0,
                                           n4, 0.000244140625f /* H0^2 exact */);
    }

    dim3 blk2(64, 4);
    dim3 gridL0((n0 + BTX - 1) / BTX, (n0 + BTY - 1) / BTY, B);   // 9 x 17 x 64

    for (int cyc = 0; cyc < 2; ++cyc) {
        // psi0 = relax^2(psi0, q0); q1 = rescal(psi0, q0)
        relax2_rescal_kernel<<<gridL0, blk2, 0, stream>>>(curA, q0, curB, q1, n0, n1, inv0, c0);
        // psi1 = relax^2(0, q1)
        {
            dim3 g((n1 + 255) / 256, n1, B), blk(256);
            relax2_zero_kernel<<<g, blk, 0, stream>>>(q1, psi1, n1, inv1);
        }
        // psi0 = relax^2(psi0 + prolong(psi1), q0)
        relax2_prolong_kernel<<<gridL0, blk2, 0, stream>>>(curB, q0, psi1, curA, n0, n1, inv0);
    }
}

// Round 8
// 622.269 us; speedup vs baseline: 1.0509x; 1.0509x over previous
//
#include <hip/hip_runtime.h>

// Helmholtz multigrid (MREFIN=6, NU1=NU2=2, NCYC=2) on 64x1x513x513 f32.
// Round 7 == Round 4/5/6 resubmission (infra timeouts; no data to justify edits).
// Structure: DCE'd schedule (6 launches), div-free tiled kernels, q0 scale
// folded into reads, init kernel eliminated, LDS-tiled relax2_zero.
// Live work per cycle:
//   psi0 = relax^2(psi0,q0); q1 = rescal(psi0,q0); psi1 = relax^2(0,q1);
//   psi0 = relax^2(psi0 + prolong(psi1), q0)

// ---------------- level-0 downsweep: relax^2 + rescal ----------------
__global__ __launch_bounds__(256) void relax2_rescal_kernel(
    const float* __restrict__ pin, const float* __restrict__ qraw,
    float* __restrict__ pout, float* __restrict__ qc,
    float inv, float c, float qs)
{
    const int n = 513, nc = 257;
    __shared__ float sp[21][72];   // raw pin, rows [0,21) cols [0,69)
    __shared__ float s1[20][72];   // stage1,  rows [1,20) cols [1,68)
    __shared__ float s2[19][72];   // stage2,  rows [2,19) cols [2,67)
    const int tx = threadIdx.x, ty = threadIdx.y;   // (64,4)
    const int bx0 = blockIdx.x * 64, by0 = blockIdx.y * 16;
    const int gx0 = bx0 - 3, gy0 = by0 - 3;
    const size_t base = (size_t)blockIdx.z * (n * n);

    // Phase A: stage raw pin
    for (int r = 0; r < 6; ++r) {
        int ly = ty + 4 * r;
        if (ly >= 21) break;
        int gy = gy0 + ly;
        bool rok = (gy >= 0 && gy < n);
        const float* row = pin + base + (size_t)gy * n;
        int gx = gx0 + tx;
        sp[ly][tx] = (rok && gx >= 0 && gx < n) ? row[gx] : 0.0f;
        if (tx < 5) {
            int lx = 64 + tx; gx = gx0 + lx;
            sp[ly][lx] = (rok && gx >= 0 && gx < n) ? row[gx] : 0.0f;
        }
    }
    __syncthreads();

    // Phase B: stage1 = relax(pin)
    for (int r = 0; r < 5; ++r) {
        int ly = 1 + ty + 4 * r;
        if (ly >= 20) break;
        int gy = gy0 + ly;
        bool iy = (gy >= 1 && gy < n - 1);
        {
            int lx = 1 + tx, gx = gx0 + lx;
            float v = 0.0f;
            if (iy && gx >= 1 && gx < n - 1) {
                float qv = qraw[base + (size_t)gy * n + gx] * qs;
                v = inv * ((((sp[ly-1][lx] + sp[ly+1][lx]) + sp[ly][lx-1]) + sp[ly][lx+1]) - qv);
            }
            s1[ly][lx] = v;
        }
        if (tx < 3) {
            int lx = 65 + tx, gx = gx0 + lx;
            float v = 0.0f;
            if (iy && gx >= 1 && gx < n - 1) {
                float qv = qraw[base + (size_t)gy * n + gx] * qs;
                v = inv * ((((sp[ly-1][lx] + sp[ly+1][lx]) + sp[ly][lx-1]) + sp[ly][lx+1]) - qv);
            }
            s1[ly][lx] = v;
        }
    }
    __syncthreads();

    // Phase C: stage2 = relax(stage1)
    for (int r = 0; r < 5; ++r) {
        int ly = 2 + ty + 4 * r;
        if (ly >= 19) break;
        int gy = gy0 + ly;
        bool iy = (gy >= 1 && gy < n - 1);
        {
            int lx = 2 + tx, gx = gx0 + lx;
            float v = 0.0f;
            if (iy && gx >= 1 && gx < n - 1) {
                float qv = qraw[base + (size_t)gy * n + gx] * qs;
                v = inv * ((((s1[ly-1][lx] + s1[ly+1][lx]) + s1[ly][lx-1]) + s1[ly][lx+1]) - qv);
            }
            s2[ly][lx] = v;
        }
        if (tx < 1) {
            int lx = 66, gx = gx0 + lx;
            float v = 0.0f;
            if (iy && gx >= 1 && gx < n - 1) {
                float qv = qraw[base + (size_t)gy * n + gx] * qs;
                v = inv * ((((s1[ly-1][lx] + s1[ly+1][lx]) + s1[ly][lx-1]) + s1[ly][lx+1]) - qv);
            }
            s2[ly][lx] = v;
        }
    }
    __syncthreads();

    // Phase D: write relaxed psi
    for (int r = 0; r < 4; ++r) {
        int ly = 3 + ty + 4 * r;           // 3..18
        int gy = gy0 + ly;                 // by0 + ty + 4r
        if (gy >= n) continue;
        int lx = 3 + tx, gx = gx0 + lx;    // bx0 + tx
        if (gx >= n) continue;
        pout[base + (size_t)gy * n + gx] = s2[ly][lx];
    }

    // Phase E: rescal from LDS stage2 (8x32 coarse points per block)
    {
        int tid = ty * 64 + tx;
        int lyc = tid >> 5, lxc = tid & 31;
        int fy = by0 + 2 * lyc, fx = bx0 + 2 * lxc;
        if (fy < n && fx < n) {
            int ic = fy >> 1, jc = fx >> 1;
            float outv = 0.0f;
            if (ic > 0 && ic < nc - 1 && jc > 0 && jc < nc - 1) {
                int ly = 2 * lyc + 3, lx = 2 * lxc + 3;
                float qv = qraw[base + (size_t)fy * n + fx] * qs;
                float ctr = s2[ly][lx];
                float up  = s2[ly-1][lx];
                float dn  = s2[ly+1][lx];
                float lf  = s2[ly][lx-1];
                float rt  = s2[ly][lx+1];
                outv = 4.0f * (((((c * ctr - up) - dn) - lf) - rt) + qv);
            }
            qc[(size_t)blockIdx.z * (nc * nc) + (size_t)ic * nc + jc] = outv;
        }
    }
}

// ---------------- level-1: psi1 = relax^2(0, q1), LDS-tiled ----------------
__global__ __launch_bounds__(256) void relax2_zero_kernel(
    const float* __restrict__ q, float* __restrict__ pout, float inv)
{
    const int n = 257;
    __shared__ float sq[18][68];   // q,      rows [0,18) cols [0,66)
    __shared__ float s1[18][68];   // stage1 = interior ? inv*(0-q) : 0
    const int tx = threadIdx.x, ty = threadIdx.y;   // (64,4)
    const int bx0 = blockIdx.x * 64, by0 = blockIdx.y * 16;
    const int gx0 = bx0 - 1, gy0 = by0 - 1;
    const size_t base = (size_t)blockIdx.z * (n * n);

    // Phase A: stage q and pointwise stage1 together
    for (int r = 0; r < 5; ++r) {
        int ly = ty + 4 * r;
        if (ly >= 18) break;
        int gy = gy0 + ly;
        bool rok = (gy >= 0 && gy < n);
        bool iy = (gy >= 1 && gy < n - 1);
        #pragma unroll
        for (int seg = 0; seg < 2; ++seg) {
            if (seg == 1 && tx >= 2) break;
            int lx = seg == 0 ? tx : 64 + tx;
            int gx = gx0 + lx;
            float qv = 0.0f, v = 0.0f;
            if (rok && gx >= 0 && gx < n) {
                qv = q[base + (size_t)gy * n + gx];
                if (iy && gx >= 1 && gx < n - 1) v = inv * (0.0f - qv);
            }
            sq[ly][lx] = qv;
            s1[ly][lx] = v;
        }
    }
    __syncthreads();

    // Phase B: stage2 -> global
    for (int r = 0; r < 4; ++r) {
        int ly = 1 + ty + 4 * r;           // 1..16
        int gy = gy0 + ly;                 // by0 + ty + 4r
        if (gy >= n) continue;
        int lx = 1 + tx, gx = gx0 + lx;    // bx0 + tx
        if (gx >= n) continue;
        float v = 0.0f;
        if (gy >= 1 && gy < n - 1 && gx >= 1 && gx < n - 1)
            v = inv * ((((s1[ly-1][lx] + s1[ly+1][lx]) + s1[ly][lx-1]) + s1[ly][lx+1])
                       - sq[ly][lx]);
        pout[base + (size_t)gy * n + gx] = v;
    }
}

// ---------------- level-0 upsweep: relax^2(pin + prolong(coarse)) ----------------
__global__ __launch_bounds__(256) void relax2_prolong_kernel(
    const float* __restrict__ pin, const float* __restrict__ qraw,
    const float* __restrict__ coarse, float* __restrict__ pout,
    float inv, float qs)
{
    const int n = 513, nc = 257;
    __shared__ float sp[20][72];   // pe = pin + prolong, rows [0,20) cols [0,68)
    __shared__ float s1[19][72];   // stage1, rows [1,19) cols [1,67)
    const int tx = threadIdx.x, ty = threadIdx.y;
    const int bx0 = blockIdx.x * 64, by0 = blockIdx.y * 16;
    const int gx0 = bx0 - 2, gy0 = by0 - 2;
    const size_t base = (size_t)blockIdx.z * (n * n);
    const size_t cb = (size_t)blockIdx.z * (nc * nc);

    // Phase A: pe = pin + bilinear(coarse)
    for (int r = 0; r < 5; ++r) {
        int ly = ty + 4 * r;               // 0..19 exact
        int gy = gy0 + ly;
        bool rok = (gy >= 0 && gy < n);
        #pragma unroll
        for (int seg = 0; seg < 2; ++seg) {
            if (seg == 1 && tx >= 4) break;
            int lx = seg == 0 ? tx : 64 + tx;
            int gx = gx0 + lx;
            float v = 0.0f;
            if (rok && gx >= 0 && gx < n) {
                size_t p = base + (size_t)gy * n + gx;
                int ci = gy >> 1, cj = gx >> 1;
                int io = gy & 1, jo = gx & 1;
                int cip = (ci + 1 < nc) ? ci + 1 : nc - 1;
                int cjp = (cj + 1 < nc) ? cj + 1 : nc - 1;
                const float* cr0 = coarse + cb + (size_t)ci * nc;
                const float* cr1 = coarse + cb + (size_t)cip * nc;
                float v00 = cr0[cj], v01 = cr0[cjp];
                float v10 = cr1[cj], v11 = cr1[cjp];
                float top = jo ? 0.5f * (v00 + v01) : v00;
                float bot = jo ? 0.5f * (v10 + v11) : v10;
                float pv = io ? 0.5f * (top + bot) : top;
                v = pin[p] + pv;
            }
            sp[ly][lx] = v;
        }
    }
    __syncthreads();

    // Phase B: stage1 = relax(pe)
    for (int r = 0; r < 5; ++r) {
        int ly = 1 + ty + 4 * r;
        if (ly >= 19) break;
        int gy = gy0 + ly;
        bool iy = (gy >= 1 && gy < n - 1);
        {
            int lx = 1 + tx, gx = gx0 + lx;
            float v = 0.0f;
            if (iy && gx >= 1 && gx < n - 1) {
                float qv = qraw[base + (size_t)gy * n + gx] * qs;
                v = inv * ((((sp[ly-1][lx] + sp[ly+1][lx]) + sp[ly][lx-1]) + sp[ly][lx+1]) - qv);
            }
            s1[ly][lx] = v;
        }
        if (tx < 2) {
            int lx = 65 + tx, gx = gx0 + lx;
            float v = 0.0f;
            if (iy && gx >= 1 && gx < n - 1) {
                float qv = qraw[base + (size_t)gy * n + gx] * qs;
                v = inv * ((((sp[ly-1][lx] + sp[ly+1][lx]) + sp[ly][lx-1]) + sp[ly][lx+1]) - qv);
            }
            s1[ly][lx] = v;
        }
    }
    __syncthreads();

    // Phase C: stage2 -> global
    for (int r = 0; r < 4; ++r) {
        int ly = 2 + ty + 4 * r;           // 2..17
        int gy = gy0 + ly;                 // by0 + ty + 4r
        if (gy >= n) continue;
        int lx = 2 + tx, gx = gx0 + lx;    // bx0 + tx
        if (gx >= n) continue;
        float v = 0.0f;
        if (gy >= 1 && gy < n - 1 && gx >= 1 && gx < n - 1) {
            float qv = qraw[base + (size_t)gy * n + gx] * qs;
            v = inv * ((((s1[ly-1][lx] + s1[ly+1][lx]) + s1[ly][lx-1]) + s1[ly][lx+1]) - qv);
        }
        pout[base + (size_t)gy * n + gx] = v;
    }
}

extern "C" void kernel_launch(void* const* d_in, const int* in_sizes, int n_in,
                              void* d_out, int out_size, void* d_ws, size_t ws_size,
                              hipStream_t stream) {
    const float* PSIG = (const float*)d_in[0];
    const float* QIN  = (const float*)d_in[1];
    float* out = (float*)d_out;
    float* ws  = (float*)d_ws;

    const int B = 64;
    const int n0 = 513, n1 = 257;
    const double h0 = 0.015625, h1 = 0.03125;
    const float inv0 = (float)(1.0 / (4.0 + h0 * h0));
    const float c0   = (float)(4.0 + h0 * h0);
    const float inv1 = (float)(1.0 / (4.0 + h1 * h1));
    const float qs0  = 0.000244140625f;   // np.float32(h0^2), exact
    const size_t E0 = (size_t)B * n0 * n0;
    const size_t E1 = (size_t)B * n1 * n1;

    size_t off = 0;
    auto alloc = [&](size_t e) -> float* {
        float* p = ws + off;
        off += (e + 63) & ~(size_t)63;
        return p;
    };
    float* q1   = alloc(E1);
    float* psi1 = alloc(E1);
    float* bufB = alloc(E0);

    dim3 blk2(64, 4);
    dim3 gridL0(9, 33, B);    // ceil(513/64) x ceil(513/16) x batch
    dim3 gridL1(5, 17, B);    // ceil(257/64) x ceil(257/16) x batch

    const float* down_src[2] = {PSIG, out};
    for (int cyc = 0; cyc < 2; ++cyc) {
        // psi0 = relax^2(psi0, q0); q1 = rescal(psi0, q0)   [q0 folded from QIN]
        relax2_rescal_kernel<<<gridL0, blk2, 0, stream>>>(down_src[cyc], QIN, bufB, q1,
                                                          inv0, c0, qs0);
        // psi1 = relax^2(0, q1)
        relax2_zero_kernel<<<gridL1, blk2, 0, stream>>>(q1, psi1, inv1);
        // psi0 = relax^2(psi0 + prolong(psi1), q0)
        relax2_prolong_kernel<<<gridL0, blk2, 0, stream>>>(bufB, QIN, psi1, out,
                                                           inv0, qs0);
    }
}

// Round 10
// 398.995 us; speedup vs baseline: 1.6389x; 1.5596x over previous
//
#include <hip/hip_runtime.h>

// Helmholtz multigrid (MREFIN=6, NU1=NU2=2, NCYC=2) on 64x1x513x513 f32.
// Round 10 == Round 9 resubmission (infra timeout; audit found no defects).
// Register-rolling column-walk kernels (no LDS, no barriers) replacing the
// DS-pipe-bound 3-phase LDS tiling (R8 post-mortem: 16 scalar LDS ops/pt
// x 5.8cyc = the whole 164us). One wave spans the full 513-wide row (64 lanes
// x 8 cols); p/q/s1/s2 rows roll through registers; x-neighbor exchange via 2
// shuffles/row; padded-stride (520/260) ws buffers make float4 stores aligned.
// Live work per cycle (DCE'd schedule, verified R3/R8):
//   psi0 = relax^2(psi0,q0); q1 = rescal(psi0,q0); psi1 = relax^2(0,q1);
//   psi0 = relax^2(psi0 + prolong(psi1), q0)

#define PS0 520   // padded stride for level-0 ws buffer (513 rows)
#define PSC 260   // padded stride for coarse buffers (257 rows)

static __device__ __forceinline__ void zero8(float (&r)[8]) {
    #pragma unroll
    for (int e = 0; e < 8; ++e) r[e] = 0.f;
}

// load fine row from a 513-stride array (+ col-512 broadcast); zeros if OOB row
static __device__ __forceinline__ void load_row513(const float* __restrict__ p, int y, int x0,
                                                   float (&r)[8], float& rE) {
    if ((unsigned)y > 512u) { zero8(r); rE = 0.f; return; }
    const float* row = p + (size_t)y * 513;
    #pragma unroll
    for (int e = 0; e < 8; ++e) r[e] = row[x0 + e];
    rE = row[512];
}

static __device__ __forceinline__ void load_q513(const float* __restrict__ p, int y, int x0,
                                                 float qs, float (&r)[8]) {
    if ((unsigned)y > 512u) { zero8(r); return; }
    const float* row = p + (size_t)y * 513;
    #pragma unroll
    for (int e = 0; e < 8; ++e) r[e] = row[x0 + e] * qs;
}

// one relax row: out = interior ? inv*((((up+dn)+lf)+rt) - q) : 0
// cur spans x = 8*lane..8*lane+7; curE = value at x=512 of the cur row.
static __device__ __forceinline__ void relax_row(const float (&up)[8], const float (&cur)[8],
                                                 const float (&dn)[8], float curE,
                                                 const float (&q)[8], float (&out)[8],
                                                 int y, int lane, float inv) {
    float lf = __shfl_up(cur[7], 1);     // lane t-1's x=8t-1
    float rt = __shfl_down(cur[0], 1);   // lane t+1's x=8t+8
    if (lane == 63) rt = curE;
    if (y <= 0 || y >= 512) { zero8(out); return; }
    out[0] = inv * ((((up[0] + dn[0]) + lf) + cur[1]) - q[0]);
    #pragma unroll
    for (int e = 1; e < 7; ++e)
        out[e] = inv * ((((up[e] + dn[e]) + cur[e - 1]) + cur[e + 1]) - q[e]);
    out[7] = inv * ((((up[7] + dn[7]) + cur[6]) + rt) - q[7]);
    if (lane == 0) out[0] = 0.f;         // x=0 boundary
}

// ---------------- level-0 downsweep: relax^2 + rescal, register walk ----------------
__global__ __launch_bounds__(64) void down_kernel(
    const float* __restrict__ pin,    // stride 513 (PSIG or d_out)
    const float* __restrict__ qraw,   // QIN, stride 513 (scaled by qs on load)
    float* __restrict__ pout,         // bufB, stride 520
    float* __restrict__ qc,           // q1, stride 260
    float inv, float cc, float qs)
{
    const int lane = threadIdx.x;
    const int gy0 = blockIdx.y * 16;           // strip output rows gy0..gy0+15
    const int x0 = lane * 8;
    const float* p_src = pin  + (size_t)blockIdx.z * (513u * 513u);
    const float* q_src = qraw + (size_t)blockIdx.z * (513u * 513u);
    float* p_dst = pout + (size_t)blockIdx.z * (513u * PS0);
    float* c_dst = qc   + (size_t)blockIdx.z * (257u * PSC);

    float pA[8], pB[8], pC[8], pN[8];          // p rows y, y+1, y+2, (incoming y+3)
    float pBE, pCE, pNE, tE;
    float qA[8], qB[8], qC[8], qN[8];          // q rows y-1, y, y+1, (incoming y+2)
    float s1A[8], s1B[8], s1C[8], s1N[8];      // s1 rows (warm-up A), y-1, y, (new y+1)
    float s2A[8], s2B[8], s2C[8];              // s2 rows y-2, y-1, (new y)
    float tq[8];

    // ---- warm-up: build s1[gy0-1], s1[gy0], s2[gy0-1] ----
    load_row513(p_src, gy0 - 3, x0, pA, tE);
    load_row513(p_src, gy0 - 2, x0, pB, pBE);
    load_row513(p_src, gy0 - 1, x0, pC, pCE);
    load_q513(q_src, gy0 - 2, x0, qs, tq);
    relax_row(pA, pB, pC, pBE, tq, s1A, gy0 - 2, lane, inv);
    #pragma unroll
    for (int e = 0; e < 8; ++e) { pA[e] = pB[e]; pB[e] = pC[e]; }
    pBE = pCE;
    load_row513(p_src, gy0, x0, pC, pCE);
    load_q513(q_src, gy0 - 1, x0, qs, qA);
    relax_row(pA, pB, pC, pBE, qA, s1B, gy0 - 1, lane, inv);
    #pragma unroll
    for (int e = 0; e < 8; ++e) { pA[e] = pB[e]; pB[e] = pC[e]; }
    pBE = pCE;
    load_row513(p_src, gy0 + 1, x0, pC, pCE);
    load_q513(q_src, gy0, x0, qs, qB);
    relax_row(pA, pB, pC, pBE, qB, s1C, gy0, lane, inv);
    relax_row(s1A, s1B, s1C, 0.f, qA, s2B, gy0 - 1, lane, inv);
    #pragma unroll
    for (int e = 0; e < 8; ++e) { pA[e] = pB[e]; pB[e] = pC[e]; }
    pBE = pCE;
    load_row513(p_src, gy0 + 2, x0, pC, pCE);
    load_q513(q_src, gy0 + 1, x0, qs, qC);
    zero8(s2A);
    // invariant entering iter y: pA=p[y],pB=p[y+1],pC=p[y+2]; qA=q[y-1],qB=q[y],qC=q[y+1]

    const int ylim = (gy0 + 15 <= 512) ? gy0 + 15 : 512;
    for (int y = gy0; y <= ylim; ++y) {
        load_row513(p_src, y + 3, x0, pN, pNE);      // prefetch, used next iter
        load_q513(q_src, y + 2, x0, qs, qN);
        relax_row(pA, pB, pC, pBE, qC, s1N, y + 1, lane, inv);   // s1[y+1]
        relax_row(s1B, s1C, s1N, 0.f, qB, s2C, y, lane, inv);    // s2[y]
        {   // store psi row y (aligned float4: (y*520+8t)*4 % 16 == 0)
            float* row = p_dst + (size_t)y * PS0;
            *(float4*)(row + x0)     = make_float4(s2C[0], s2C[1], s2C[2], s2C[3]);
            *(float4*)(row + x0 + 4) = make_float4(s2C[4], s2C[5], s2C[6], s2C[7]);
            if (lane == 63) row[512] = 0.f;
        }
        if (y & 1) {   // fy = y-1 even: rescal coarse row ic = fy/2
            const int ic = (y - 1) >> 1;
            float lf0 = __shfl_up(s2B[7], 1);
            float o0 = 4.f * (((((cc * s2B[0] - s2A[0]) - s2C[0]) - lf0    ) - s2B[1]) + qA[0]);
            float o1 = 4.f * (((((cc * s2B[2] - s2A[2]) - s2C[2]) - s2B[1]) - s2B[3]) + qA[2]);
            float o2 = 4.f * (((((cc * s2B[4] - s2A[4]) - s2C[4]) - s2B[3]) - s2B[5]) + qA[4]);
            float o3 = 4.f * (((((cc * s2B[6] - s2A[6]) - s2C[6]) - s2B[5]) - s2B[7]) + qA[6]);
            if (ic == 0) { o0 = 0.f; o1 = 0.f; o2 = 0.f; o3 = 0.f; }   // ring row
            if (lane == 0) o0 = 0.f;                                    // jc=0 ring col
            *(float4*)(c_dst + (size_t)ic * PSC + 4 * lane) = make_float4(o0, o1, o2, o3);
        }
        #pragma unroll
        for (int e = 0; e < 8; ++e) {
            pA[e] = pB[e]; pB[e] = pC[e]; pC[e] = pN[e];
            qA[e] = qB[e]; qB[e] = qC[e]; qC[e] = qN[e];
            s1B[e] = s1C[e]; s1C[e] = s1N[e];
            s2A[e] = s2B[e]; s2B[e] = s2C[e];
        }
        pBE = pCE; pCE = pNE;
    }
}

// column-interp a coarse row (stride PSC) to fine-x registers: civ[e] at x=8*lane+e
static __device__ __forceinline__ void colinterp_row(const float* __restrict__ c_src, int ci, int lane,
                                                     float (&civ)[8], float& civE) {
    if (ci > 256) { zero8(civ); civE = 0.f; return; }
    const float* row = c_src + (size_t)ci * PSC;
    float4 cv = *(const float4*)(row + 4 * lane);   // coarse cols 4t..4t+3 (aligned)
    float cR = row[256];
    float c4 = __shfl_down(cv.x, 1);                // coarse col 4t+4
    if (lane == 63) c4 = cR;
    civ[0] = cv.x; civ[1] = 0.5f * (cv.x + cv.y);
    civ[2] = cv.y; civ[3] = 0.5f * (cv.y + cv.z);
    civ[4] = cv.z; civ[5] = 0.5f * (cv.z + cv.w);
    civ[6] = cv.w; civ[7] = 0.5f * (cv.w + c4);
    civE = cR;                                      // fine x=512 (even)
}

// ---------------- level-0 upsweep: relax^2(pin + prolong(coarse)), register walk ----------------
__global__ __launch_bounds__(64) void up_kernel(
    const float* __restrict__ pin,    // bufB, stride 520
    const float* __restrict__ qraw,   // QIN, stride 513
    const float* __restrict__ coarse, // psi1, stride 260
    float* __restrict__ pout,         // d_out, stride 513
    float inv, float qs)
{
    const int lane = threadIdx.x;
    const int gy0 = blockIdx.y * 16;
    const int x0 = lane * 8;
    const float* p_src = pin    + (size_t)blockIdx.z * (513u * PS0);
    const float* q_src = qraw   + (size_t)blockIdx.z * (513u * 513u);
    const float* c_src = coarse + (size_t)blockIdx.z * (257u * PSC);
    float* p_dst = pout + (size_t)blockIdx.z * (513u * 513u);

    // rolling column-interped coarse rows cl=civ[cci], ch=civ[cci+1]
    int cci = (gy0 >= 3) ? ((gy0 - 3) >> 1) : 0;
    float cl[8], ch[8]; float clE, chE;
    colinterp_row(c_src, cci, lane, cl, clE);
    colinterp_row(c_src, cci + 1, lane, ch, chE);

    // pe row = pin + bilinear(coarse); rows requested in strictly increasing y
    auto loadPE = [&](int y, float (&r)[8], float& rE) {
        if ((unsigned)y > 512u) { zero8(r); rE = 0.f; return; }
        const int ci = y >> 1;
        if (cci < ci) {
            #pragma unroll
            for (int e = 0; e < 8; ++e) cl[e] = ch[e];
            clE = chE; ++cci;
            colinterp_row(c_src, cci + 1, lane, ch, chE);
        }
        const float* row = p_src + (size_t)y * PS0;
        float4 a = *(const float4*)(row + x0);
        float4 b = *(const float4*)(row + x0 + 4);
        float pv[8] = {a.x, a.y, a.z, a.w, b.x, b.y, b.z, b.w};
        float pE = row[512];
        if (y & 1) {
            #pragma unroll
            for (int e = 0; e < 8; ++e) r[e] = pv[e] + 0.5f * (cl[e] + ch[e]);
            rE = pE + 0.5f * (clE + chE);
        } else {
            #pragma unroll
            for (int e = 0; e < 8; ++e) r[e] = pv[e] + cl[e];
            rE = pE + clE;
        }
    };

    float pA[8], pB[8], pC[8], pN[8];
    float pBE, pCE, pNE, tE;
    float qA[8], qB[8], qC[8], qN[8];
    float s1A[8], s1B[8], s1C[8], s1N[8];
    float s2A[8], s2B[8], s2C[8];   // s2A kept for symmetry (cheap), only B/C used
    float tq[8];

    // ---- warm-up ----
    loadPE(gy0 - 3, pA, tE);
    loadPE(gy0 - 2, pB, pBE);
    loadPE(gy0 - 1, pC, pCE);
    load_q513(q_src, gy0 - 2, x0, qs, tq);
    relax_row(pA, pB, pC, pBE, tq, s1A, gy0 - 2, lane, inv);
    #pragma unroll
    for (int e = 0; e < 8; ++e) { pA[e] = pB[e]; pB[e] = pC[e]; }
    pBE = pCE;
    loadPE(gy0, pC, pCE);
    load_q513(q_src, gy0 - 1, x0, qs, qA);
    relax_row(pA, pB, pC, pBE, qA, s1B, gy0 - 1, lane, inv);
    #pragma unroll
    for (int e = 0; e < 8; ++e) { pA[e] = pB[e]; pB[e] = pC[e]; }
    pBE = pCE;
    loadPE(gy0 + 1, pC, pCE);
    load_q513(q_src, gy0, x0, qs, qB);
    relax_row(pA, pB, pC, pBE, qB, s1C, gy0, lane, inv);
    relax_row(s1A, s1B, s1C, 0.f, qA, s2B, gy0 - 1, lane, inv);
    #pragma unroll
    for (int e = 0; e < 8; ++e) { pA[e] = pB[e]; pB[e] = pC[e]; }
    pBE = pCE;
    loadPE(gy0 + 2, pC, pCE);
    load_q513(q_src, gy0 + 1, x0, qs, qC);
    zero8(s2A);

    const int ylim = (gy0 + 15 <= 512) ? gy0 + 15 : 512;
    for (int y = gy0; y <= ylim; ++y) {
        loadPE(y + 3, pN, pNE);
        load_q513(q_src, y + 2, x0, qs, qN);
        relax_row(pA, pB, pC, pBE, qC, s1N, y + 1, lane, inv);
        relax_row(s1B, s1C, s1N, 0.f, qB, s2C, y, lane, inv);
        {   // store to d_out (stride 513): scalar stores, L1/L2 combine
            float* row = p_dst + (size_t)y * 513;
            #pragma unroll
            for (int e = 0; e < 8; ++e) row[x0 + e] = s2C[e];
            if (lane == 63) row[512] = 0.f;
        }
        #pragma unroll
        for (int e = 0; e < 8; ++e) {
            pA[e] = pB[e]; pB[e] = pC[e]; pC[e] = pN[e];
            qA[e] = qB[e]; qB[e] = qC[e]; qC[e] = qN[e];
            s1B[e] = s1C[e]; s1C[e] = s1N[e];
            s2A[e] = s2B[e]; s2B[e] = s2C[e];
        }
        pBE = pCE; pCE = pNE;
    }
}

// ---------------- level-1: psi1 = relax^2(0, q1), LDS-tiled (small, R8-verified) ----------------
__global__ __launch_bounds__(256) void relax2_zero_kernel(
    const float* __restrict__ q, float* __restrict__ pout, float inv)
{
    const int n = 257;
    __shared__ float sq[18][68];
    __shared__ float s1[18][68];
    const int tx = threadIdx.x, ty = threadIdx.y;   // (64,4)
    const int bx0 = blockIdx.x * 64, by0 = blockIdx.y * 16;
    const int gx0 = bx0 - 1, gy0 = by0 - 1;
    const size_t base = (size_t)blockIdx.z * (257u * PSC);

    for (int r = 0; r < 5; ++r) {
        int ly = ty + 4 * r;
        if (ly >= 18) break;
        int gy = gy0 + ly;
        bool rok = (gy >= 0 && gy < n);
        bool iy = (gy >= 1 && gy < n - 1);
        #pragma unroll
        for (int seg = 0; seg < 2; ++seg) {
            if (seg == 1 && tx >= 2) break;
            int lx = seg == 0 ? tx : 64 + tx;
            int gx = gx0 + lx;
            float qv = 0.0f, v = 0.0f;
            if (rok && gx >= 0 && gx < n) {
                qv = q[base + (size_t)gy * PSC + gx];
                if (iy && gx >= 1 && gx < n - 1) v = inv * (0.0f - qv);
            }
            sq[ly][lx] = qv;
            s1[ly][lx] = v;
        }
    }
    __syncthreads();

    for (int r = 0; r < 4; ++r) {
        int ly = 1 + ty + 4 * r;
        int gy = gy0 + ly;
        if (gy >= n) continue;
        int lx = 1 + tx, gx = gx0 + lx;
        if (gx >= n) continue;
        float v = 0.0f;
        if (gy >= 1 && gy < n - 1 && gx >= 1 && gx < n - 1)
            v = inv * ((((s1[ly-1][lx] + s1[ly+1][lx]) + s1[ly][lx-1]) + s1[ly][lx+1])
                       - sq[ly][lx]);
        pout[base + (size_t)gy * PSC + gx] = v;
    }
}

extern "C" void kernel_launch(void* const* d_in, const int* in_sizes, int n_in,
                              void* d_out, int out_size, void* d_ws, size_t ws_size,
                              hipStream_t stream) {
    const float* PSIG = (const float*)d_in[0];
    const float* QIN  = (const float*)d_in[1];
    float* out = (float*)d_out;
    float* ws  = (float*)d_ws;

    const double h0 = 0.015625, h1 = 0.03125;
    const float inv0 = (float)(1.0 / (4.0 + h0 * h0));
    const float c0   = (float)(4.0 + h0 * h0);
    const float inv1 = (float)(1.0 / (4.0 + h1 * h1));
    const float qs0  = 0.000244140625f;   // np.float32(h0^2), exact

    const size_t PLC = (size_t)257 * PSC * 64;   // q1/psi1 floats (17.1 MB each)
    float* q1   = ws;
    float* psi1 = ws + PLC;
    float* bufB = ws + 2 * PLC;                  // 513x520x64 floats (68.3 MB); total ~102.5 MB

    dim3 gBig(1, 33, 64), bBig(64);              // 1-wave blocks, 16-row strips, gy0=0..512
    dim3 gZ(5, 17, 64), bZ(64, 4);

    for (int cyc = 0; cyc < 2; ++cyc) {
        const float* src = cyc ? (const float*)out : PSIG;
        // psi0 = relax^2(psi0, q0); q1 = rescal(psi0, q0)
        down_kernel<<<gBig, bBig, 0, stream>>>(src, QIN, bufB, q1, inv0, c0, qs0);
        // psi1 = relax^2(0, q1)
        relax2_zero_kernel<<<gZ, bZ, 0, stream>>>(q1, psi1, inv1);
        // psi0 = relax^2(psi0 + prolong(psi1), q0)  -> d_out (also cyc-0 intermediate)
        up_kernel<<<gBig, bBig, 0, stream>>>(bufB, QIN, psi1, out, inv0, qs0);
    }
}